// Round 3
// baseline (2240.741 us; speedup 1.0000x reference)
//
#include <hip/hip_runtime.h>
#include <hip/hip_bf16.h>
#include <cstdint>

#define F_IN 128
#define F_HID 64

__device__ __forceinline__ float bf2f(unsigned short u) {
  return __uint_as_float(((unsigned int)u) << 16);
}
__device__ __forceinline__ unsigned short f2bf(float f) {
  unsigned int u = __float_as_uint(f);
  u += 0x7FFFu + ((u >> 16) & 1u);   // round-to-nearest-even
  return (unsigned short)(u >> 16);
}

// ---------------- dtype detection ----------------
// Inspect low 16 bits of 256 32-bit words of `feature`. If the array is bf16,
// those are real bf16 values from N(0,1): exponent field in [117,137] for
// ~99.9% of samples. If the array is fp32, they are low mantissa bits:
// exponent field uniform -> in range only ~8% of the time.
__global__ __launch_bounds__(64) void k_detect(const unsigned int* __restrict__ Xw,
                                               int* __restrict__ flag) {
  int lane = threadIdx.x;  // 64
  int cnt = 0;
  for (int t = lane; t < 256; t += 64) {
    unsigned int ex = (Xw[t] >> 7) & 0xFFu;
    cnt += (ex >= 117u && ex <= 137u) ? 1 : 0;
  }
#pragma unroll
  for (int off = 32; off > 0; off >>= 1) cnt += __shfl_xor(cnt, off, 64);
  if (lane == 0) *flag = (cnt >= 128) ? 1 : 0;  // 1 = bf16, 0 = fp32
}

// ---------------- degree / dinv ----------------
__global__ __launch_bounds__(256) void k_init_deg(float* __restrict__ deg, int N) {
  int t = blockIdx.x * 256 + threadIdx.x;
  if (t < N) deg[t] = 1.0f;  // self-loop
}

__global__ __launch_bounds__(256) void k_edge_deg(const int* __restrict__ dst,
                                                  float* __restrict__ deg, int E) {
  int t = blockIdx.x * 256 + threadIdx.x;
  int stride = gridDim.x * 256;
  for (; t < E; t += stride) atomicAdd(deg + dst[t], 1.0f);
}

__global__ __launch_bounds__(256) void k_rsqrt(float* __restrict__ deg, int N) {
  int t = blockIdx.x * 256 + threadIdx.x;
  if (t < N) deg[t] = rsqrtf(deg[t]);  // deg >= 1
}

// ---------------- GEMM1: A = (X @ W1) * dinv[row] ----------------
template <bool ISB>
__device__ __forceinline__ void gemm1_body(const void* __restrict__ Xv,
                                           const float* __restrict__ sW,
                                           const float* __restrict__ dinv,
                                           float* __restrict__ A, int N,
                                           int lane, int wave) {
  const int RPW = 8;
  for (int r0 = (blockIdx.x * 4 + wave) * RPW; r0 < N; r0 += gridDim.x * 4 * RPW) {
    float acc[RPW];
#pragma unroll
    for (int r = 0; r < RPW; r++) acc[r] = 0.f;
    for (int k4 = 0; k4 < F_IN / 4; ++k4) {
      float w0 = sW[(k4 * 4 + 0) * F_HID + lane];
      float w1 = sW[(k4 * 4 + 1) * F_HID + lane];
      float w2 = sW[(k4 * 4 + 2) * F_HID + lane];
      float w3 = sW[(k4 * 4 + 3) * F_HID + lane];
#pragma unroll
      for (int r = 0; r < RPW; r++) {
        int rr = r0 + r; rr = rr < N ? rr : N - 1;
        float x0, x1, x2, x3;
        if (ISB) {
          ushort4 xv = *reinterpret_cast<const ushort4*>(
              (const unsigned short*)Xv + (size_t)rr * F_IN + k4 * 4);
          x0 = bf2f(xv.x); x1 = bf2f(xv.y); x2 = bf2f(xv.z); x3 = bf2f(xv.w);
        } else {
          float4 xv = *reinterpret_cast<const float4*>(
              (const float*)Xv + (size_t)rr * F_IN + k4 * 4);
          x0 = xv.x; x1 = xv.y; x2 = xv.z; x3 = xv.w;
        }
        acc[r] += x0 * w0 + x1 * w1 + x2 * w2 + x3 * w3;
      }
    }
#pragma unroll
    for (int r = 0; r < RPW; r++) {
      int rr = r0 + r;
      if (rr < N) A[(size_t)rr * F_HID + lane] = acc[r] * dinv[rr];
    }
  }
}

__global__ __launch_bounds__(256) void k_gemm1(const void* __restrict__ Xv,
                                               const void* __restrict__ Wv,
                                               const float* __restrict__ dinv,
                                               float* __restrict__ A, int N,
                                               const int* __restrict__ flagp) {
  __shared__ float sW[F_IN * F_HID];  // 32 KB
  const bool isb = (*flagp != 0);
  int tid = threadIdx.x;
  for (int t = tid; t < F_IN * F_HID; t += 256)
    sW[t] = isb ? bf2f(((const unsigned short*)Wv)[t]) : ((const float*)Wv)[t];
  __syncthreads();
  const int lane = tid & 63;
  const int wave = tid >> 6;
  if (isb) gemm1_body<true>(Xv, sW, dinv, A, N, lane, wave);
  else     gemm1_body<false>(Xv, sW, dinv, A, N, lane, wave);
}

// ---------------- GEMM2: Bout = (Xin @ W2) * dinv[row]   (Xin fp32 N x 64) ----------------
__global__ __launch_bounds__(256) void k_gemm2(const float* __restrict__ Xin,
                                               const void* __restrict__ Wv,
                                               const float* __restrict__ dinv,
                                               float* __restrict__ Bout, int N,
                                               const int* __restrict__ flagp) {
  __shared__ float sW[F_HID * F_HID];  // 16 KB
  const bool isb = (*flagp != 0);
  int tid = threadIdx.x;
  for (int t = tid; t < F_HID * F_HID; t += 256)
    sW[t] = isb ? bf2f(((const unsigned short*)Wv)[t]) : ((const float*)Wv)[t];
  __syncthreads();
  const int lane = tid & 63;
  const int wave = tid >> 6;
  const int RPW = 8;
  for (int r0 = (blockIdx.x * 4 + wave) * RPW; r0 < N; r0 += gridDim.x * 4 * RPW) {
    float acc[RPW];
#pragma unroll
    for (int r = 0; r < RPW; r++) acc[r] = 0.f;
    for (int k4 = 0; k4 < F_HID / 4; ++k4) {
      float w0 = sW[(k4 * 4 + 0) * F_HID + lane];
      float w1 = sW[(k4 * 4 + 1) * F_HID + lane];
      float w2 = sW[(k4 * 4 + 2) * F_HID + lane];
      float w3 = sW[(k4 * 4 + 3) * F_HID + lane];
#pragma unroll
      for (int r = 0; r < RPW; r++) {
        int rr = r0 + r; rr = rr < N ? rr : N - 1;
        float4 xv = *reinterpret_cast<const float4*>(Xin + (size_t)rr * F_HID + k4 * 4);
        acc[r] += xv.x * w0 + xv.y * w1 + xv.z * w2 + xv.w * w3;
      }
    }
#pragma unroll
    for (int r = 0; r < RPW; r++) {
      int rr = r0 + r;
      if (rr < N) Bout[(size_t)rr * F_HID + lane] = acc[r] * dinv[rr];
    }
  }
}

// ---------------- scatter: AGG[dst] += H[src]   (wave per edge, lane per feature) ----------------
__global__ __launch_bounds__(256) void k_scatter(const int* __restrict__ src,
                                                 const int* __restrict__ dst,
                                                 const float* __restrict__ H,
                                                 float* __restrict__ AGG, int E) {
  int lane = threadIdx.x & 63;
  int gw = (blockIdx.x * 256 + threadIdx.x) >> 6;
  int nW = (gridDim.x * 256) >> 6;
  for (int e = gw; e < E; e += nW) {
    int s = src[e], d = dst[e];
    float v = H[(size_t)s * F_HID + lane];
    atomicAdd(AGG + (size_t)d * F_HID + lane, v);
  }
}

// ---------------- epilogue 1: A = relu((AGG + A) * dinv + b1) ----------------
__global__ __launch_bounds__(256) void k_epi1(const float* __restrict__ AGG,
                                              float* __restrict__ A,
                                              const float* __restrict__ dinv,
                                              const void* __restrict__ b1,
                                              int N, const int* __restrict__ flagp) {
  int t = blockIdx.x * 256 + threadIdx.x;  // over N*16 float4s
  if (t >= N * 16) return;
  const bool isb = (*flagp != 0);
  int n = t >> 4;
  int c4 = t & 15;
  float bv[4];
#pragma unroll
  for (int c = 0; c < 4; c++)
    bv[c] = isb ? bf2f(((const unsigned short*)b1)[c4 * 4 + c])
                : ((const float*)b1)[c4 * 4 + c];
  float4 g = reinterpret_cast<const float4*>(AGG)[t];
  float4 a = reinterpret_cast<const float4*>(A)[t];
  float dv = dinv[n];
  float4 o;
  o.x = fmaxf((g.x + a.x) * dv + bv[0], 0.f);
  o.y = fmaxf((g.y + a.y) * dv + bv[1], 0.f);
  o.z = fmaxf((g.z + a.z) * dv + bv[2], 0.f);
  o.w = fmaxf((g.w + a.w) * dv + bv[3], 0.f);
  reinterpret_cast<float4*>(A)[t] = o;
}

// ---------------- epilogue 2: B = (AGG + B) * dinv + b2 ----------------
__global__ __launch_bounds__(256) void k_epi2(const float* __restrict__ AGG,
                                              float* __restrict__ B,
                                              const float* __restrict__ dinv,
                                              const void* __restrict__ b2,
                                              int N, const int* __restrict__ flagp) {
  int t = blockIdx.x * 256 + threadIdx.x;
  if (t >= N * 16) return;
  const bool isb = (*flagp != 0);
  int n = t >> 4;
  int c4 = t & 15;
  float bv[4];
#pragma unroll
  for (int c = 0; c < 4; c++)
    bv[c] = isb ? bf2f(((const unsigned short*)b2)[c4 * 4 + c])
                : ((const float*)b2)[c4 * 4 + c];
  float4 g = reinterpret_cast<const float4*>(AGG)[t];
  float4 b = reinterpret_cast<const float4*>(B)[t];
  float dv = dinv[n];
  float4 o;
  o.x = (g.x + b.x) * dv + bv[0];
  o.y = (g.y + b.y) * dv + bv[1];
  o.z = (g.z + b.z) * dv + bv[2];
  o.w = (g.w + b.w) * dv + bv[3];
  reinterpret_cast<float4*>(B)[t] = o;
}

// ---------------- PR GEMM: PR[n][0:128] = out2[n] @ Wa ; PR[n][128:256] = out2[n] @ Wb ----------------
// LDS holds weights as bf16 (32 KB; a 64 KB fp32 tile exceeds the per-WG LDS limit).
__global__ __launch_bounds__(256) void k_gemm_pr(const float* __restrict__ Xin,
                                                 const void* __restrict__ fc1Wv,
                                                 float* __restrict__ PR, int N,
                                                 const int* __restrict__ flagp) {
  __shared__ unsigned short sW[F_HID * 256];  // 32 KB bf16
  const bool isb = (*flagp != 0);
  int tid = threadIdx.x;
  for (int t = tid; t < F_HID * 256; t += 256) {
    int k = t >> 8, h = t & 255;
    int idx = (h < 128) ? (k * 128 + h) : ((64 + k) * 128 + (h - 128));
    sW[t] = isb ? ((const unsigned short*)fc1Wv)[idx]
                : f2bf(((const float*)fc1Wv)[idx]);
  }
  __syncthreads();
  const int lane = tid & 63;
  const int wave = tid >> 6;
  const int RPW = 8;
  for (int r0 = (blockIdx.x * 4 + wave) * RPW; r0 < N; r0 += gridDim.x * 4 * RPW) {
    float acc[RPW][4];
#pragma unroll
    for (int r = 0; r < RPW; r++)
#pragma unroll
      for (int c = 0; c < 4; c++) acc[r][c] = 0.f;
    for (int k4 = 0; k4 < F_HID / 4; ++k4) {
      float w[4][4];
#pragma unroll
      for (int kk = 0; kk < 4; kk++)
#pragma unroll
        for (int c = 0; c < 4; c++)
          w[kk][c] = bf2f(sW[(k4 * 4 + kk) * 256 + c * 64 + lane]);
#pragma unroll
      for (int r = 0; r < RPW; r++) {
        int rr = r0 + r; rr = rr < N ? rr : N - 1;
        float4 xv = *reinterpret_cast<const float4*>(Xin + (size_t)rr * F_HID + k4 * 4);
#pragma unroll
        for (int c = 0; c < 4; c++)
          acc[r][c] += xv.x * w[0][c] + xv.y * w[1][c] + xv.z * w[2][c] + xv.w * w[3][c];
      }
    }
#pragma unroll
    for (int r = 0; r < RPW; r++) {
      int rr = r0 + r;
      if (rr < N) {
#pragma unroll
        for (int c = 0; c < 4; c++)
          PR[(size_t)rr * 256 + c * 64 + lane] = acc[r][c];
      }
    }
  }
}

// ---------------- query: out[q] = relu(P[i[q]] + R[j[q]] + fc1_b) @ fc2_W + fc2_b ----------------
// 16 lanes per query, 4 queries per wave. Lane m covers hid elements 8m..8m+7.
__global__ __launch_bounds__(256) void k_query(const float* __restrict__ PR,
                                               const int* __restrict__ qi,
                                               const int* __restrict__ qj,
                                               const void* __restrict__ fc1b,
                                               const void* __restrict__ fc2W,
                                               const void* __restrict__ fc2b,
                                               void* __restrict__ out, int Q,
                                               const int* __restrict__ flagp) {
  const bool isb = (*flagp != 0);
  int tid = threadIdx.x;
  int lane = tid & 63;
  int wave = tid >> 6;
  int g = lane >> 4, m = lane & 15;
  float bb[8], w0[8], w1[8];
#pragma unroll
  for (int t = 0; t < 8; t++) {
    int h = m * 8 + t;
    if (isb) {
      bb[t] = bf2f(((const unsigned short*)fc1b)[h]);
      w0[t] = bf2f(((const unsigned short*)fc2W)[h * 2 + 0]);
      w1[t] = bf2f(((const unsigned short*)fc2W)[h * 2 + 1]);
    } else {
      bb[t] = ((const float*)fc1b)[h];
      w0[t] = ((const float*)fc2W)[h * 2 + 0];
      w1[t] = ((const float*)fc2W)[h * 2 + 1];
    }
  }
  float ob0 = isb ? bf2f(((const unsigned short*)fc2b)[0]) : ((const float*)fc2b)[0];
  float ob1 = isb ? bf2f(((const unsigned short*)fc2b)[1]) : ((const float*)fc2b)[1];
  int gw = blockIdx.x * 4 + wave;
  int nW = gridDim.x * 4;
  int nQuad = (Q + 3) >> 2;
  for (int quad = gw; quad < nQuad; quad += nW) {
    int q = quad * 4 + g;
    int qq = q < Q ? q : Q - 1;
    int iq = qi[qq], jq = qj[qq];
    const float4* Pr = reinterpret_cast<const float4*>(PR + (size_t)iq * 256);
    const float4* Rr = reinterpret_cast<const float4*>(PR + (size_t)jq * 256 + 128);
    float4 pa = Pr[m * 2], pb = Pr[m * 2 + 1];
    float4 ra = Rr[m * 2], rb = Rr[m * 2 + 1];
    float h[8] = {pa.x + ra.x, pa.y + ra.y, pa.z + ra.z, pa.w + ra.w,
                  pb.x + rb.x, pb.y + rb.y, pb.z + rb.z, pb.w + rb.w};
    float r0 = 0.f, r1 = 0.f;
#pragma unroll
    for (int t = 0; t < 8; t++) {
      float hv = fmaxf(h[t] + bb[t], 0.f);
      r0 += hv * w0[t];
      r1 += hv * w1[t];
    }
#pragma unroll
    for (int off = 8; off > 0; off >>= 1) {
      r0 += __shfl_xor(r0, off, 16);
      r1 += __shfl_xor(r1, off, 16);
    }
    if (m == 0 && q < Q) {
      if (isb) {
        *reinterpret_cast<ushort2*>((unsigned short*)out + (size_t)q * 2) =
            make_ushort2(f2bf(r0 + ob0), f2bf(r1 + ob1));
      } else {
        *reinterpret_cast<float2*>((float*)out + (size_t)q * 2) =
            make_float2(r0 + ob0, r1 + ob1);
      }
    }
  }
}

extern "C" void kernel_launch(void* const* d_in, const int* in_sizes, int n_in,
                              void* d_out, int out_size, void* d_ws, size_t ws_size,
                              hipStream_t stream) {
  const void* X    = d_in[0];                    // feature, N x 128 (bf16 or fp32)
  const int*  edges= (const int*)d_in[1];        // [2, E]
  const int*  qi   = (const int*)d_in[2];
  const int*  qj   = (const int*)d_in[3];
  const void* W1   = d_in[4];                    // 128 x 64
  const void* b1   = d_in[5];                    // 64
  const void* W2   = d_in[6];                    // 64 x 64
  const void* b2   = d_in[7];                    // 64
  const void* fc1W = d_in[8];                    // 128 x 128
  const void* fc1b = d_in[9];                    // 128
  const void* fc2W = d_in[10];                   // 128 x 2
  const void* fc2b = d_in[11];                   // 2

  const int N = in_sizes[0] / F_IN;
  const int E = in_sizes[1] / 2;
  const int Q = in_sizes[2];

  char* ws = (char*)d_ws;
  size_t off = 0;
  auto alloc = [&](size_t bytes) -> void* {
    void* p = ws + off;
    off += (bytes + 255) & ~(size_t)255;
    return p;
  };
  int*   flag = (int*)alloc(4);
  float* dinv = (float*)alloc((size_t)N * 4);
  float* A    = (float*)alloc((size_t)N * F_HID * 4);   // Hs1 -> out1 -> agg2
  float* B    = (float*)alloc((size_t)N * F_HID * 4);   // agg1 -> Hs2 -> out2
  float* PR   = (float*)alloc((size_t)N * 256 * 4);     // [P | R]
  (void)ws_size; (void)n_in; (void)out_size;

  const int* esrc = edges;
  const int* edst = edges + E;

  const int gN = (N + 255) / 256;
  const int gNF = (N * 16 + 255) / 256;

  k_detect<<<1, 64, 0, stream>>>((const unsigned int*)X, flag);

  k_init_deg<<<gN, 256, 0, stream>>>(dinv, N);
  k_edge_deg<<<2048, 256, 0, stream>>>(edst, dinv, E);
  k_rsqrt<<<gN, 256, 0, stream>>>(dinv, N);

  // layer 1
  k_gemm1<<<1024, 256, 0, stream>>>(X, W1, dinv, A, N, flag);
  hipMemsetAsync(B, 0, (size_t)N * F_HID * 4, stream);
  k_scatter<<<8192, 256, 0, stream>>>(esrc, edst, A, B, E);
  k_epi1<<<gNF, 256, 0, stream>>>(B, A, dinv, b1, N, flag);

  // layer 2
  k_gemm2<<<1024, 256, 0, stream>>>(A, W2, dinv, B, N, flag);
  hipMemsetAsync(A, 0, (size_t)N * F_HID * 4, stream);
  k_scatter<<<8192, 256, 0, stream>>>(esrc, edst, B, A, E);
  k_epi2<<<gNF, 256, 0, stream>>>(A, B, dinv, b2, N, flag);

  // MLP factorization: PR = out2 @ [Wa | Wb]
  k_gemm_pr<<<1024, 256, 0, stream>>>(B, fc1W, PR, N, flag);

  // per-query: gather P[i] + R[j], relu, fc2
  k_query<<<4096, 256, 0, stream>>>(PR, qi, qj, fc1b, fc2W, fc2b, d_out, Q, flag);
}

// Round 4
// 1371.234 us; speedup vs baseline: 1.6341x; 1.6341x over previous
//
#include <hip/hip_runtime.h>
#include <hip/hip_bf16.h>
#include <cstdint>

#define F_IN 128
#define F_HID 64

__device__ __forceinline__ float bf2f(unsigned short u) {
  return __uint_as_float(((unsigned int)u) << 16);
}
__device__ __forceinline__ unsigned short f2bf(float f) {
  unsigned int u = __float_as_uint(f);
  u += 0x7FFFu + ((u >> 16) & 1u);   // round-to-nearest-even
  return (unsigned short)(u >> 16);
}

// ---------------- dtype detection (unchanged from round 3 — it resolved bf16) ----------------
__global__ __launch_bounds__(64) void k_detect(const unsigned int* __restrict__ Xw,
                                               int* __restrict__ flag) {
  int lane = threadIdx.x;  // 64
  int cnt = 0;
  for (int t = lane; t < 256; t += 64) {
    unsigned int ex = (Xw[t] >> 7) & 0xFFu;
    cnt += (ex >= 117u && ex <= 137u) ? 1 : 0;
  }
#pragma unroll
  for (int off = 32; off > 0; off >>= 1) cnt += __shfl_xor(cnt, off, 64);
  if (lane == 0) *flag = (cnt >= 128) ? 1 : 0;  // 1 = bf16, 0 = fp32
}

// ---------------- CSR build ----------------
__global__ __launch_bounds__(256) void k_hist(const int* __restrict__ dst,
                                              int* __restrict__ cnt, int E) {
  int t = blockIdx.x * 256 + threadIdx.x;
  int stride = gridDim.x * 256;
  for (; t < E; t += stride) atomicAdd(cnt + dst[t], 1);
}

// per-block exclusive scan (chunk = 256), block totals to bsum
__global__ __launch_bounds__(256) void k_scan_block(const int* __restrict__ cnt,
                                                    int* __restrict__ excl,
                                                    int* __restrict__ bsum, int N) {
  __shared__ int s[256];
  int t = threadIdx.x;
  int i = blockIdx.x * 256 + t;
  int v = (i < N) ? cnt[i] : 0;
  s[t] = v;
  __syncthreads();
#pragma unroll
  for (int d = 1; d < 256; d <<= 1) {
    int x = (t >= d) ? s[t - d] : 0;
    __syncthreads();
    s[t] += x;
    __syncthreads();
  }
  if (i < N) excl[i] = s[t] - v;
  if (t == 255) bsum[blockIdx.x] = s[255];
}

__global__ void k_scan_bsum(int* __restrict__ bsum, int nb) {
  if (threadIdx.x == 0 && blockIdx.x == 0) {
    int acc = 0;
    for (int b = 0; b < nb; b++) { int v = bsum[b]; bsum[b] = acc; acc += v; }
  }
}

__global__ __launch_bounds__(256) void k_scan_add(int* __restrict__ excl,
                                                  const int* __restrict__ bsum, int N) {
  int i = blockIdx.x * 256 + threadIdx.x;
  if (i < N) excl[i] += bsum[blockIdx.x];
}

// fill: off[] holds exclusive starts; after fill, off[n] == segment end
__global__ __launch_bounds__(256) void k_fill(const int* __restrict__ src,
                                              const int* __restrict__ dst,
                                              int* __restrict__ off,
                                              int* __restrict__ csr, int E) {
  int t = blockIdx.x * 256 + threadIdx.x;
  int stride = gridDim.x * 256;
  for (; t < E; t += stride) {
    int d = dst[t];
    int p = atomicAdd(off + d, 1);
    csr[p] = src[t];
  }
}

__global__ __launch_bounds__(256) void k_dinv(const int* __restrict__ cnt,
                                              float* __restrict__ dinv, int N) {
  int t = blockIdx.x * 256 + threadIdx.x;
  if (t < N) dinv[t] = rsqrtf((float)cnt[t] + 1.0f);  // +1 self-loop
}

// ---------------- GEMM1: A = (X @ W1) * dinv[row] ----------------
template <bool ISB>
__device__ __forceinline__ void gemm1_body(const void* __restrict__ Xv,
                                           const float* __restrict__ sW,
                                           const float* __restrict__ dinv,
                                           float* __restrict__ A, int N,
                                           int lane, int wave) {
  const int RPW = 8;
  for (int r0 = (blockIdx.x * 4 + wave) * RPW; r0 < N; r0 += gridDim.x * 4 * RPW) {
    float acc[RPW];
#pragma unroll
    for (int r = 0; r < RPW; r++) acc[r] = 0.f;
    for (int k4 = 0; k4 < F_IN / 4; ++k4) {
      float w0 = sW[(k4 * 4 + 0) * F_HID + lane];
      float w1 = sW[(k4 * 4 + 1) * F_HID + lane];
      float w2 = sW[(k4 * 4 + 2) * F_HID + lane];
      float w3 = sW[(k4 * 4 + 3) * F_HID + lane];
#pragma unroll
      for (int r = 0; r < RPW; r++) {
        int rr = r0 + r; rr = rr < N ? rr : N - 1;
        float x0, x1, x2, x3;
        if (ISB) {
          ushort4 xv = *reinterpret_cast<const ushort4*>(
              (const unsigned short*)Xv + (size_t)rr * F_IN + k4 * 4);
          x0 = bf2f(xv.x); x1 = bf2f(xv.y); x2 = bf2f(xv.z); x3 = bf2f(xv.w);
        } else {
          float4 xv = *reinterpret_cast<const float4*>(
              (const float*)Xv + (size_t)rr * F_IN + k4 * 4);
          x0 = xv.x; x1 = xv.y; x2 = xv.z; x3 = xv.w;
        }
        acc[r] += x0 * w0 + x1 * w1 + x2 * w2 + x3 * w3;
      }
    }
#pragma unroll
    for (int r = 0; r < RPW; r++) {
      int rr = r0 + r;
      if (rr < N) A[(size_t)rr * F_HID + lane] = acc[r] * dinv[rr];
    }
  }
}

__global__ __launch_bounds__(256) void k_gemm1(const void* __restrict__ Xv,
                                               const void* __restrict__ Wv,
                                               const float* __restrict__ dinv,
                                               float* __restrict__ A, int N,
                                               const int* __restrict__ flagp) {
  __shared__ float sW[F_IN * F_HID];  // 32 KB
  const bool isb = (*flagp != 0);
  int tid = threadIdx.x;
  for (int t = tid; t < F_IN * F_HID; t += 256)
    sW[t] = isb ? bf2f(((const unsigned short*)Wv)[t]) : ((const float*)Wv)[t];
  __syncthreads();
  const int lane = tid & 63;
  const int wave = tid >> 6;
  if (isb) gemm1_body<true>(Xv, sW, dinv, A, N, lane, wave);
  else     gemm1_body<false>(Xv, sW, dinv, A, N, lane, wave);
}

// ---------------- GEMM2: Bout = (Xin @ W2) * dinv[row]   (Xin fp32 N x 64) ----------------
__global__ __launch_bounds__(256) void k_gemm2(const float* __restrict__ Xin,
                                               const void* __restrict__ Wv,
                                               const float* __restrict__ dinv,
                                               float* __restrict__ Bout, int N,
                                               const int* __restrict__ flagp) {
  __shared__ float sW[F_HID * F_HID];  // 16 KB
  const bool isb = (*flagp != 0);
  int tid = threadIdx.x;
  for (int t = tid; t < F_HID * F_HID; t += 256)
    sW[t] = isb ? bf2f(((const unsigned short*)Wv)[t]) : ((const float*)Wv)[t];
  __syncthreads();
  const int lane = tid & 63;
  const int wave = tid >> 6;
  const int RPW = 8;
  for (int r0 = (blockIdx.x * 4 + wave) * RPW; r0 < N; r0 += gridDim.x * 4 * RPW) {
    float acc[RPW];
#pragma unroll
    for (int r = 0; r < RPW; r++) acc[r] = 0.f;
    for (int k4 = 0; k4 < F_HID / 4; ++k4) {
      float w0 = sW[(k4 * 4 + 0) * F_HID + lane];
      float w1 = sW[(k4 * 4 + 1) * F_HID + lane];
      float w2 = sW[(k4 * 4 + 2) * F_HID + lane];
      float w3 = sW[(k4 * 4 + 3) * F_HID + lane];
#pragma unroll
      for (int r = 0; r < RPW; r++) {
        int rr = r0 + r; rr = rr < N ? rr : N - 1;
        float4 xv = *reinterpret_cast<const float4*>(Xin + (size_t)rr * F_HID + k4 * 4);
        acc[r] += xv.x * w0 + xv.y * w1 + xv.z * w2 + xv.w * w3;
      }
    }
#pragma unroll
    for (int r = 0; r < RPW; r++) {
      int rr = r0 + r;
      if (rr < N) Bout[(size_t)rr * F_HID + lane] = acc[r] * dinv[rr];
    }
  }
}

// ---------------- aggregate (CSR gather): AGG[n] = sum_{e in seg(n)} H[csr[e]] ----------------
// One wave per node; coalesced 64-wide index loads, shfl broadcast, row reads
// are 256 B coalesced. No atomics: one plain write per node row.
__global__ __launch_bounds__(256) void k_agg(const int* __restrict__ csr,
                                             const int* __restrict__ off_end,
                                             const int* __restrict__ cnt,
                                             const float* __restrict__ H,
                                             float* __restrict__ AGG, int N) {
  int lane = threadIdx.x & 63;
  int gw = (blockIdx.x * 256 + threadIdx.x) >> 6;
  int nW = (gridDim.x * 256) >> 6;
  for (int n = gw; n < N; n += nW) {
    int end = off_end[n];
    int start = end - cnt[n];
    float acc0 = 0.f, acc1 = 0.f;
    for (int e0 = start; e0 < end; e0 += 64) {
      int ee = e0 + lane;
      int idx = (ee < end) ? csr[ee] : 0;
      int m = end - e0; m = m < 64 ? m : 64;
      int k = 0;
      for (; k + 3 < m; k += 4) {
        int s0 = __shfl(idx, k, 64);
        int s1 = __shfl(idx, k + 1, 64);
        int s2 = __shfl(idx, k + 2, 64);
        int s3 = __shfl(idx, k + 3, 64);
        float v0 = H[(size_t)s0 * F_HID + lane];
        float v1 = H[(size_t)s1 * F_HID + lane];
        float v2 = H[(size_t)s2 * F_HID + lane];
        float v3 = H[(size_t)s3 * F_HID + lane];
        acc0 += v0 + v2;
        acc1 += v1 + v3;
      }
      for (; k < m; k++) {
        int s0 = __shfl(idx, k, 64);
        acc0 += H[(size_t)s0 * F_HID + lane];
      }
    }
    AGG[(size_t)n * F_HID + lane] = acc0 + acc1;
  }
}

// ---------------- epilogue 1: A = relu((AGG + A) * dinv + b1) ----------------
__global__ __launch_bounds__(256) void k_epi1(const float* __restrict__ AGG,
                                              float* __restrict__ A,
                                              const float* __restrict__ dinv,
                                              const void* __restrict__ b1,
                                              int N, const int* __restrict__ flagp) {
  int t = blockIdx.x * 256 + threadIdx.x;  // over N*16 float4s
  if (t >= N * 16) return;
  const bool isb = (*flagp != 0);
  int n = t >> 4;
  int c4 = t & 15;
  float bv[4];
#pragma unroll
  for (int c = 0; c < 4; c++)
    bv[c] = isb ? bf2f(((const unsigned short*)b1)[c4 * 4 + c])
                : ((const float*)b1)[c4 * 4 + c];
  float4 g = reinterpret_cast<const float4*>(AGG)[t];
  float4 a = reinterpret_cast<const float4*>(A)[t];
  float dv = dinv[n];
  float4 o;
  o.x = fmaxf((g.x + a.x) * dv + bv[0], 0.f);
  o.y = fmaxf((g.y + a.y) * dv + bv[1], 0.f);
  o.z = fmaxf((g.z + a.z) * dv + bv[2], 0.f);
  o.w = fmaxf((g.w + a.w) * dv + bv[3], 0.f);
  reinterpret_cast<float4*>(A)[t] = o;
}

// ---------------- epilogue 2: B = (AGG + B) * dinv + b2 ----------------
__global__ __launch_bounds__(256) void k_epi2(const float* __restrict__ AGG,
                                              float* __restrict__ B,
                                              const float* __restrict__ dinv,
                                              const void* __restrict__ b2,
                                              int N, const int* __restrict__ flagp) {
  int t = blockIdx.x * 256 + threadIdx.x;
  if (t >= N * 16) return;
  const bool isb = (*flagp != 0);
  int n = t >> 4;
  int c4 = t & 15;
  float bv[4];
#pragma unroll
  for (int c = 0; c < 4; c++)
    bv[c] = isb ? bf2f(((const unsigned short*)b2)[c4 * 4 + c])
                : ((const float*)b2)[c4 * 4 + c];
  float4 g = reinterpret_cast<const float4*>(AGG)[t];
  float4 b = reinterpret_cast<const float4*>(B)[t];
  float dv = dinv[n];
  float4 o;
  o.x = (g.x + b.x) * dv + bv[0];
  o.y = (g.y + b.y) * dv + bv[1];
  o.z = (g.z + b.z) * dv + bv[2];
  o.w = (g.w + b.w) * dv + bv[3];
  reinterpret_cast<float4*>(B)[t] = o;
}

// ---------------- PR GEMM: PR[n][0:128] = out2[n] @ Wa ; PR[n][128:256] = out2[n] @ Wb ----------------
__global__ __launch_bounds__(256) void k_gemm_pr(const float* __restrict__ Xin,
                                                 const void* __restrict__ fc1Wv,
                                                 float* __restrict__ PR, int N,
                                                 const int* __restrict__ flagp) {
  __shared__ unsigned short sW[F_HID * 256];  // 32 KB bf16
  const bool isb = (*flagp != 0);
  int tid = threadIdx.x;
  for (int t = tid; t < F_HID * 256; t += 256) {
    int k = t >> 8, h = t & 255;
    int idx = (h < 128) ? (k * 128 + h) : ((64 + k) * 128 + (h - 128));
    sW[t] = isb ? ((const unsigned short*)fc1Wv)[idx]
                : f2bf(((const float*)fc1Wv)[idx]);
  }
  __syncthreads();
  const int lane = tid & 63;
  const int wave = tid >> 6;
  const int RPW = 8;
  for (int r0 = (blockIdx.x * 4 + wave) * RPW; r0 < N; r0 += gridDim.x * 4 * RPW) {
    float acc[RPW][4];
#pragma unroll
    for (int r = 0; r < RPW; r++)
#pragma unroll
      for (int c = 0; c < 4; c++) acc[r][c] = 0.f;
    for (int k4 = 0; k4 < F_HID / 4; ++k4) {
      float w[4][4];
#pragma unroll
      for (int kk = 0; kk < 4; kk++)
#pragma unroll
        for (int c = 0; c < 4; c++)
          w[kk][c] = bf2f(sW[(k4 * 4 + kk) * 256 + c * 64 + lane]);
#pragma unroll
      for (int r = 0; r < RPW; r++) {
        int rr = r0 + r; rr = rr < N ? rr : N - 1;
        float4 xv = *reinterpret_cast<const float4*>(Xin + (size_t)rr * F_HID + k4 * 4);
#pragma unroll
        for (int c = 0; c < 4; c++)
          acc[r][c] += xv.x * w[0][c] + xv.y * w[1][c] + xv.z * w[2][c] + xv.w * w[3][c];
      }
    }
#pragma unroll
    for (int r = 0; r < RPW; r++) {
      int rr = r0 + r;
      if (rr < N) {
#pragma unroll
        for (int c = 0; c < 4; c++)
          PR[(size_t)rr * 256 + c * 64 + lane] = acc[r][c];
      }
    }
  }
}

// ---------------- query: out[q] = relu(P[i[q]] + R[j[q]] + fc1_b) @ fc2_W + fc2_b ----------------
__global__ __launch_bounds__(256) void k_query(const float* __restrict__ PR,
                                               const int* __restrict__ qi,
                                               const int* __restrict__ qj,
                                               const void* __restrict__ fc1b,
                                               const void* __restrict__ fc2W,
                                               const void* __restrict__ fc2b,
                                               void* __restrict__ out, int Q,
                                               const int* __restrict__ flagp) {
  const bool isb = (*flagp != 0);
  int tid = threadIdx.x;
  int lane = tid & 63;
  int wave = tid >> 6;
  int g = lane >> 4, m = lane & 15;
  float bb[8], w0[8], w1[8];
#pragma unroll
  for (int t = 0; t < 8; t++) {
    int h = m * 8 + t;
    if (isb) {
      bb[t] = bf2f(((const unsigned short*)fc1b)[h]);
      w0[t] = bf2f(((const unsigned short*)fc2W)[h * 2 + 0]);
      w1[t] = bf2f(((const unsigned short*)fc2W)[h * 2 + 1]);
    } else {
      bb[t] = ((const float*)fc1b)[h];
      w0[t] = ((const float*)fc2W)[h * 2 + 0];
      w1[t] = ((const float*)fc2W)[h * 2 + 1];
    }
  }
  float ob0 = isb ? bf2f(((const unsigned short*)fc2b)[0]) : ((const float*)fc2b)[0];
  float ob1 = isb ? bf2f(((const unsigned short*)fc2b)[1]) : ((const float*)fc2b)[1];
  int gw = blockIdx.x * 4 + wave;
  int nW = gridDim.x * 4;
  int nQuad = (Q + 3) >> 2;
  for (int quad = gw; quad < nQuad; quad += nW) {
    int q = quad * 4 + g;
    int qq = q < Q ? q : Q - 1;
    int iq = qi[qq], jq = qj[qq];
    const float4* Pr = reinterpret_cast<const float4*>(PR + (size_t)iq * 256);
    const float4* Rr = reinterpret_cast<const float4*>(PR + (size_t)jq * 256 + 128);
    float4 pa = Pr[m * 2], pb = Pr[m * 2 + 1];
    float4 ra = Rr[m * 2], rb = Rr[m * 2 + 1];
    float h[8] = {pa.x + ra.x, pa.y + ra.y, pa.z + ra.z, pa.w + ra.w,
                  pb.x + rb.x, pb.y + rb.y, pb.z + rb.z, pb.w + rb.w};
    float r0 = 0.f, r1 = 0.f;
#pragma unroll
    for (int t = 0; t < 8; t++) {
      float hv = fmaxf(h[t] + bb[t], 0.f);
      r0 += hv * w0[t];
      r1 += hv * w1[t];
    }
#pragma unroll
    for (int off = 8; off > 0; off >>= 1) {
      r0 += __shfl_xor(r0, off, 16);
      r1 += __shfl_xor(r1, off, 16);
    }
    if (m == 0 && q < Q) {
      if (isb) {
        *reinterpret_cast<ushort2*>((unsigned short*)out + (size_t)q * 2) =
            make_ushort2(f2bf(r0 + ob0), f2bf(r1 + ob1));
      } else {
        *reinterpret_cast<float2*>((float*)out + (size_t)q * 2) =
            make_float2(r0 + ob0, r1 + ob1);
      }
    }
  }
}

extern "C" void kernel_launch(void* const* d_in, const int* in_sizes, int n_in,
                              void* d_out, int out_size, void* d_ws, size_t ws_size,
                              hipStream_t stream) {
  const void* X    = d_in[0];                    // feature, N x 128 (bf16 or fp32)
  const int*  edges= (const int*)d_in[1];        // [2, E]
  const int*  qi   = (const int*)d_in[2];
  const int*  qj   = (const int*)d_in[3];
  const void* W1   = d_in[4];                    // 128 x 64
  const void* b1   = d_in[5];                    // 64
  const void* W2   = d_in[6];                    // 64 x 64
  const void* b2   = d_in[7];                    // 64
  const void* fc1W = d_in[8];                    // 128 x 128
  const void* fc1b = d_in[9];                    // 128
  const void* fc2W = d_in[10];                   // 128 x 2
  const void* fc2b = d_in[11];                   // 2

  const int N = in_sizes[0] / F_IN;
  const int E = in_sizes[1] / 2;
  const int Q = in_sizes[2];

  char* ws = (char*)d_ws;
  size_t off = 0;
  auto alloc = [&](size_t bytes) -> void* {
    void* p = ws + off;
    off += (bytes + 255) & ~(size_t)255;
    return p;
  };
  int*   flag = (int*)alloc(4);
  float* dinv = (float*)alloc((size_t)N * 4);
  float* A    = (float*)alloc((size_t)N * F_HID * 4);   // Hs1 -> out1 -> agg2
  float* B    = (float*)alloc((size_t)N * F_HID * 4);   // agg1 -> Hs2 -> out2
  float* PR   = (float*)alloc((size_t)N * 256 * 4);     // [P | R]
  // CSR scratch aliases the PR region: all CSR reads finish before gemm_pr
  // writes PR (stream-ordered), so no extra ws footprint.
  char* pr_scratch = (char*)PR;
  int* cnt  = (int*)pr_scratch;                          // N ints
  int* offx = (int*)(pr_scratch + ((size_t)N * 4 + 255 & ~(size_t)255));
  int* bsum = (int*)(pr_scratch + 2 * (((size_t)N * 4 + 255) & ~(size_t)255));
  int* csr  = (int*)(pr_scratch + 2 * (((size_t)N * 4 + 255) & ~(size_t)255) + 4096);
  (void)ws_size; (void)n_in; (void)out_size;

  const int* esrc = edges;
  const int* edst = edges + E;

  const int gN = (N + 255) / 256;
  const int gNF = (N * 16 + 255) / 256;
  const int nb = gN;  // scan blocks (chunk 256)

  k_detect<<<1, 64, 0, stream>>>((const unsigned int*)X, flag);

  // CSR build (shared by both layers); also yields degrees
  hipMemsetAsync(cnt, 0, (size_t)N * 4, stream);
  k_hist<<<2048, 256, 0, stream>>>(edst, cnt, E);
  k_scan_block<<<nb, 256, 0, stream>>>(cnt, offx, bsum, N);
  k_scan_bsum<<<1, 64, 0, stream>>>(bsum, nb);
  k_scan_add<<<nb, 256, 0, stream>>>(offx, bsum, N);
  k_dinv<<<gN, 256, 0, stream>>>(cnt, dinv, N);
  k_fill<<<2048, 256, 0, stream>>>(esrc, edst, offx, csr, E);  // offx -> segment ends

  // layer 1
  k_gemm1<<<1024, 256, 0, stream>>>(X, W1, dinv, A, N, flag);
  k_agg<<<2048, 256, 0, stream>>>(csr, offx, cnt, A, B, N);
  k_epi1<<<gNF, 256, 0, stream>>>(B, A, dinv, b1, N, flag);

  // layer 2
  k_gemm2<<<1024, 256, 0, stream>>>(A, W2, dinv, B, N, flag);
  k_agg<<<2048, 256, 0, stream>>>(csr, offx, cnt, B, A, N);
  k_epi2<<<gNF, 256, 0, stream>>>(A, B, dinv, b2, N, flag);

  // MLP factorization: PR = out2 @ [Wa | Wb]   (overwrites CSR scratch — safe)
  k_gemm_pr<<<1024, 256, 0, stream>>>(B, fc1W, PR, N, flag);

  // per-query: gather P[i] + R[j], relu, fc2
  k_query<<<4096, 256, 0, stream>>>(PR, qi, qj, fc1b, fc2W, fc2b, d_out, Q, flag);
}